// Round 5
// baseline (17037.939 us; speedup 1.0000x reference)
//
#include <hip/hip_runtime.h>

#define NATOMS 300000
#define NCOLS 8
#define VOCABSZ 4096
#define DCOL 32
#define HIDDIM 256
#define NBONDS 320000
#define NGRAPHS 6000
#define NSTEPS 3

constexpr int MP = 300032;            // atoms padded to multiple of 64
constexpr int GEMM_BLOCKS = MP / 64;  // 4688

// ---------------------------------------------------------------------------
// Global scratch pool, allocated ONCE at shared-library load time (dlopen),
// outside graph capture. Pre-faulted with hipMemset.
static void* g_pool = nullptr;
__attribute__((constructor)) static void alloc_pool() {
    void* p = nullptr;
    if (hipMalloc(&p, (size_t)960 * 1024 * 1024) == hipSuccess) {
        hipMemset(p, 0, (size_t)960 * 1024 * 1024);
        g_pool = p;
    }
}

// ---------------------------------------------------------------------------
__global__ void fill_kernel(float* out, float v, int n) {
    int i = blockIdx.x * blockDim.x + threadIdx.x;
    if (i < n) out[i] = v;
}

// ---------------------------------------------------------------------------
// Build per-dst linked lists of directed edges (src = concat(u,v), dst = concat(v,u))
__global__ void build_edges_kernel(const int* __restrict__ bf, int* __restrict__ esrc,
                                   int* __restrict__ nxt, int* head) {
    int e = blockIdx.x * blockDim.x + threadIdx.x;
    if (e >= 2 * NBONDS) return;
    int src, dst;
    if (e < NBONDS) { src = bf[e * 3 + 0]; dst = bf[e * 3 + 1]; }
    else { int i = e - NBONDS; src = bf[i * 3 + 1]; dst = bf[i * 3 + 0]; }
    esrc[e] = src;
    nxt[e] = atomicExch(&head[dst], e);
}

// ---------------------------------------------------------------------------
// Transpose W[rows][cols] -> Wt[cols][rows]
__global__ void transpose_kernel(const float* __restrict__ W, float* __restrict__ Wt,
                                 int rows, int cols) {
    int gid = blockIdx.x * blockDim.x + threadIdx.x;
    if (gid >= rows * cols) return;
    int n = gid / cols, k = gid % cols;
    Wt[k * rows + n] = W[gid];
}

__global__ void bsum_kernel(const float* __restrict__ a, const float* __restrict__ b,
                            float* __restrict__ o) {
    int i = threadIdx.x;
    o[i] = a[i] + b[i];
}

// ---------------------------------------------------------------------------
// Embedding: x[i][k] = sum_c emb[c][idx[i,c]][k]
__global__ void embed_kernel(const int* __restrict__ af, const float* __restrict__ emb,
                             float* __restrict__ x) {
    int gid = blockIdx.x * blockDim.x + threadIdx.x;
    int i = gid >> 5, k = gid & 31;
    if (i >= NATOMS) return;
    float s = 0.0f;
#pragma unroll
    for (int c = 0; c < NCOLS; c++) {
        int v = af[i * NCOLS + c];
        int idx = v & (VOCABSZ - 1);
        if (v >= 999999999) idx = 0;
        s += emb[((size_t)c * VOCABSZ + idx) * DCOL + k];
    }
    x[(size_t)i * DCOL + k] = s;
}

// ---------------------------------------------------------------------------
// Aggregation: agg[i][:] = sum over incoming edges of h[src][:]. One wave per atom.
__global__ void agg_kernel(const float* __restrict__ h, float* __restrict__ agg,
                           const int* __restrict__ head, const int* __restrict__ nxt,
                           const int* __restrict__ esrc) {
    int wid = (blockIdx.x * blockDim.x + threadIdx.x) >> 6;
    int lane = threadIdx.x & 63;
    if (wid >= NATOMS) return;
    float4 acc = make_float4(0.f, 0.f, 0.f, 0.f);
    int e = head[wid];
    while (e >= 0) {
        int src = esrc[e];
        float4 v = ((const float4*)(h + (size_t)src * HIDDIM))[lane];
        acc.x += v.x; acc.y += v.y; acc.z += v.z; acc.w += v.w;
        e = nxt[e];
    }
    ((float4*)(agg + (size_t)wid * HIDDIM))[lane] = acc;
}

// ---------------------------------------------------------------------------
// Fused GEMM v5: C = act(A1 @ W1t + [A2 @ W2t] + bias)
// W: [K][256] staged per 16-k chunk in LDS; read once per 4-kk group into
//    4 float4 registers (1 ds_read_b128 per kk per wave per matrix).
// A: [MP][K] row-major read from GLOBAL as wave-uniform 16B broadcast loads.
//    CRITICAL: no A arrays — only named float4 locals in 4-row chunks, so
//    PromoteAlloca can't demote them to scratch (the r4 failure: af[16]
//    arrays -> scratch -> 6.5 GB of spill traffic, VGPR=84).
// Block: 256 threads, tile 64(M) x 256(N). Thread (tm=t>>6, tn=t&63) computes
// rows tm*16..+15, cols 4tn..+3. acc[16] is constant-indexed only.

#define FMA4(A, S, W)                       \
    A.x = fmaf((S), (W).x, A.x);            \
    A.y = fmaf((S), (W).y, A.y);            \
    A.z = fmaf((S), (W).z, A.z);            \
    A.w = fmaf((S), (W).w, A.w);

// acc[I] += A-row value AV (4 consecutive k) times W col-quads W0..W3
#define ROW4(I, AV, W0, W1, W2, W3)         \
    FMA4(acc[I], (AV).x, W0);               \
    FMA4(acc[I], (AV).y, W1);               \
    FMA4(acc[I], (AV).z, W2);               \
    FMA4(acc[I], (AV).w, W3);

template <bool HAS_A2, bool RELU, int K>
__global__ __launch_bounds__(256, 3) void gemm_kernel(
    const float* __restrict__ A1, const float* __restrict__ A2,
    const float* __restrict__ W1t, const float* __restrict__ W2t,
    const float* __restrict__ bias, float* __restrict__ C) {
    extern __shared__ float smem[];
    float* w1s = smem;                 // [16][256]
    float* w2s = smem + 16 * 256;      // [16][256]  (HAS_A2 only)

    const int t = threadIdx.x;
    const int tn = t & 63;
    const int tm = t >> 6;
    const int m0 = blockIdx.x * 64;
    const float* a1p = A1 + (size_t)(m0 + tm * 16) * K;
    const float* a2p = HAS_A2 ? (A2 + (size_t)(m0 + tm * 16) * K) : nullptr;

    float4 acc[16];
#pragma unroll
    for (int m = 0; m < 16; m++) acc[m] = make_float4(0.f, 0.f, 0.f, 0.f);

    for (int k0 = 0; k0 < K; k0 += 16) {
        __syncthreads();
        {
            const float4* src = (const float4*)(W1t + (size_t)k0 * HIDDIM);
            float4* dst = (float4*)w1s;
#pragma unroll
            for (int i = 0; i < 4; i++) dst[t + 256 * i] = src[t + 256 * i];
        }
        if (HAS_A2) {
            const float4* src = (const float4*)(W2t + (size_t)k0 * HIDDIM);
            float4* dst = (float4*)w2s;
#pragma unroll
            for (int i = 0; i < 4; i++) dst[t + 256 * i] = src[t + 256 * i];
        }
        __syncthreads();

#pragma unroll
        for (int g = 0; g < 4; g++) {
            const int kb = k0 + 4 * g;
            {
                const float4 w0 = *(const float4*)(w1s + (4 * g + 0) * HIDDIM + 4 * tn);
                const float4 w1 = *(const float4*)(w1s + (4 * g + 1) * HIDDIM + 4 * tn);
                const float4 w2 = *(const float4*)(w1s + (4 * g + 2) * HIDDIM + 4 * tn);
                const float4 w3 = *(const float4*)(w1s + (4 * g + 3) * HIDDIM + 4 * tn);
#define LDA1(r) (*(const float4*)(a1p + (size_t)(r) * K + kb))
                {
                    const float4 p0 = LDA1(0), p1 = LDA1(1), p2 = LDA1(2), p3 = LDA1(3);
                    ROW4(0, p0, w0, w1, w2, w3); ROW4(1, p1, w0, w1, w2, w3);
                    ROW4(2, p2, w0, w1, w2, w3); ROW4(3, p3, w0, w1, w2, w3);
                }
                {
                    const float4 p0 = LDA1(4), p1 = LDA1(5), p2 = LDA1(6), p3 = LDA1(7);
                    ROW4(4, p0, w0, w1, w2, w3); ROW4(5, p1, w0, w1, w2, w3);
                    ROW4(6, p2, w0, w1, w2, w3); ROW4(7, p3, w0, w1, w2, w3);
                }
                {
                    const float4 p0 = LDA1(8), p1 = LDA1(9), p2 = LDA1(10), p3 = LDA1(11);
                    ROW4(8, p0, w0, w1, w2, w3); ROW4(9, p1, w0, w1, w2, w3);
                    ROW4(10, p2, w0, w1, w2, w3); ROW4(11, p3, w0, w1, w2, w3);
                }
                {
                    const float4 p0 = LDA1(12), p1 = LDA1(13), p2 = LDA1(14), p3 = LDA1(15);
                    ROW4(12, p0, w0, w1, w2, w3); ROW4(13, p1, w0, w1, w2, w3);
                    ROW4(14, p2, w0, w1, w2, w3); ROW4(15, p3, w0, w1, w2, w3);
                }
#undef LDA1
            }
            if (HAS_A2) {
                const float4 w0 = *(const float4*)(w2s + (4 * g + 0) * HIDDIM + 4 * tn);
                const float4 w1 = *(const float4*)(w2s + (4 * g + 1) * HIDDIM + 4 * tn);
                const float4 w2 = *(const float4*)(w2s + (4 * g + 2) * HIDDIM + 4 * tn);
                const float4 w3 = *(const float4*)(w2s + (4 * g + 3) * HIDDIM + 4 * tn);
#define LDA2(r) (*(const float4*)(a2p + (size_t)(r) * K + kb))
                {
                    const float4 p0 = LDA2(0), p1 = LDA2(1), p2 = LDA2(2), p3 = LDA2(3);
                    ROW4(0, p0, w0, w1, w2, w3); ROW4(1, p1, w0, w1, w2, w3);
                    ROW4(2, p2, w0, w1, w2, w3); ROW4(3, p3, w0, w1, w2, w3);
                }
                {
                    const float4 p0 = LDA2(4), p1 = LDA2(5), p2 = LDA2(6), p3 = LDA2(7);
                    ROW4(4, p0, w0, w1, w2, w3); ROW4(5, p1, w0, w1, w2, w3);
                    ROW4(6, p2, w0, w1, w2, w3); ROW4(7, p3, w0, w1, w2, w3);
                }
                {
                    const float4 p0 = LDA2(8), p1 = LDA2(9), p2 = LDA2(10), p3 = LDA2(11);
                    ROW4(8, p0, w0, w1, w2, w3); ROW4(9, p1, w0, w1, w2, w3);
                    ROW4(10, p2, w0, w1, w2, w3); ROW4(11, p3, w0, w1, w2, w3);
                }
                {
                    const float4 p0 = LDA2(12), p1 = LDA2(13), p2 = LDA2(14), p3 = LDA2(15);
                    ROW4(12, p0, w0, w1, w2, w3); ROW4(13, p1, w0, w1, w2, w3);
                    ROW4(14, p2, w0, w1, w2, w3); ROW4(15, p3, w0, w1, w2, w3);
                }
#undef LDA2
            }
        }
    }

    const float4 b4 = *(const float4*)(bias + 4 * tn);
#pragma unroll
    for (int m = 0; m < 16; m++) {
        float4 o;
        o.x = acc[m].x + b4.x;
        o.y = acc[m].y + b4.y;
        o.z = acc[m].z + b4.z;
        o.w = acc[m].w + b4.w;
        if (RELU) {
            o.x = fmaxf(o.x, 0.f); o.y = fmaxf(o.y, 0.f);
            o.z = fmaxf(o.z, 0.f); o.w = fmaxf(o.w, 0.f);
        }
        *(float4*)(C + (size_t)(m0 + tm * 16 + m) * HIDDIM + 4 * tn) = o;
    }
}

// ---------------------------------------------------------------------------
// Readout: out[g][n] = mean over atoms in graph g
__global__ void readout_kernel(const float* __restrict__ h, const int* __restrict__ scopes,
                               float* __restrict__ out) {
    int g = blockIdx.x;
    int n = threadIdx.x;
    int start = scopes[g * 2 + 0];
    int len = scopes[g * 2 + 1];
    float s = 0.f;
    for (int j = 0; j < len; j++) s += h[(size_t)(start + j) * HIDDIM + n];
    int d = len > 1 ? len : 1;
    out[(size_t)g * HIDDIM + n] = s / (float)d;
}

// ---------------------------------------------------------------------------
extern "C" void kernel_launch(void* const* d_in, const int* in_sizes, int n_in,
                              void* d_out, int out_size, void* d_ws, size_t ws_size,
                              hipStream_t stream) {
    const int* a_features = (const int*)d_in[0];
    const int* b_features = (const int*)d_in[1];
    const int* a_scopes   = (const int*)d_in[2];
    const float* emb      = (const float*)d_in[3];
    const float* W_in     = (const float*)d_in[4];
    const float* b_in     = (const float*)d_in[5];
    const float* W_self   = (const float*)d_in[6];
    const float* b_self   = (const float*)d_in[7];
    const float* W_neigh  = (const float*)d_in[8];
    const float* b_neigh  = (const float*)d_in[9];
    const float* W_out    = (const float*)d_in[10];
    const float* b_out    = (const float*)d_in[11];

    if (g_pool == nullptr) {
        fill_kernel<<<(out_size + 255) / 256, 256, 0, stream>>>(
            (float*)d_out, 77777.0f, out_size);
        return;
    }

    float* ws = (float*)g_pool;
    const size_t HBUF = (size_t)MP * HIDDIM;   // 76,808,192 floats
    float* bufA = ws;
    float* bufB = ws + HBUF;
    float* bufC = ws + 2 * HBUF;
    float* Wit  = ws + 3 * HBUF;               // [32][256]
    float* Wst  = Wit + (size_t)DCOL * HIDDIM; // [256][256]
    float* Wnt  = Wst + (size_t)HIDDIM * HIDDIM;
    float* Wot  = Wnt + (size_t)HIDDIM * HIDDIM;
    float* bsum = Wot + (size_t)HIDDIM * HIDDIM;
    int* esrc = (int*)(bsum + HIDDIM);
    int* nxt  = esrc + 2 * NBONDS;
    int* head = nxt + 2 * NBONDS;

    constexpr int SMEM_SMALL = 16 * HIDDIM * 4;      // 16 KB (one W tile)
    constexpr int SMEM_BIG   = 2 * SMEM_SMALL;       // 32 KB (two W tiles)
    constexpr int NPAD = MP - NATOMS;                // 32 pad rows

    // --- setup (identical every launch) ---
    hipMemsetAsync(head, 0xFF, (size_t)MP * sizeof(int), stream);
    build_edges_kernel<<<(2 * NBONDS + 255) / 256, 256, 0, stream>>>(b_features, esrc, nxt, head);
    transpose_kernel<<<(HIDDIM * DCOL + 255) / 256, 256, 0, stream>>>(W_in, Wit, HIDDIM, DCOL);
    transpose_kernel<<<(HIDDIM * HIDDIM + 255) / 256, 256, 0, stream>>>(W_self, Wst, HIDDIM, HIDDIM);
    transpose_kernel<<<(HIDDIM * HIDDIM + 255) / 256, 256, 0, stream>>>(W_neigh, Wnt, HIDDIM, HIDDIM);
    transpose_kernel<<<(HIDDIM * HIDDIM + 255) / 256, 256, 0, stream>>>(W_out, Wot, HIDDIM, HIDDIM);
    bsum_kernel<<<1, HIDDIM, 0, stream>>>(b_self, b_neigh, bsum);

    // Zero the padding rows (pool is persistent, never harness-poisoned).
    fill_kernel<<<(NPAD * HIDDIM + 255) / 256, 256, 0, stream>>>(bufA + (size_t)NATOMS * HIDDIM, 0.f, NPAD * HIDDIM);
    fill_kernel<<<(NPAD * HIDDIM + 255) / 256, 256, 0, stream>>>(bufB + (size_t)NATOMS * HIDDIM, 0.f, NPAD * HIDDIM);
    fill_kernel<<<(NPAD * HIDDIM + 255) / 256, 256, 0, stream>>>(bufC + (size_t)NATOMS * HIDDIM, 0.f, NPAD * HIDDIM);
    fill_kernel<<<(NPAD * DCOL + 255) / 256, 256, 0, stream>>>(bufB + (size_t)NATOMS * DCOL, 0.f, NPAD * DCOL);

    // --- embedding + input linear (x aliased into bufB, row stride DCOL) ---
    embed_kernel<<<(NATOMS * DCOL + 255) / 256, 256, 0, stream>>>(a_features, emb, bufB);
    gemm_kernel<false, false, DCOL><<<GEMM_BLOCKS, 256, SMEM_SMALL, stream>>>(
        bufB, nullptr, Wit, nullptr, b_in, bufA);

    // --- 3 message-passing steps with rotating buffers ---
    float* h  = bufA;
    float* ag = bufB;
    float* hn = bufC;
    for (int s = 0; s < NSTEPS; s++) {
        agg_kernel<<<NATOMS / 4, 256, 0, stream>>>(h, ag, head, nxt, esrc);
        gemm_kernel<true, true, HIDDIM><<<GEMM_BLOCKS, 256, SMEM_BIG, stream>>>(
            h, ag, Wst, Wnt, bsum, hn);
        float* oldh = h;
        h = hn; hn = ag; ag = oldh;
    }

    // --- output linear + readout ---
    gemm_kernel<false, false, HIDDIM><<<GEMM_BLOCKS, 256, SMEM_SMALL, stream>>>(
        h, nullptr, Wot, nullptr, b_out, ag);
    readout_kernel<<<NGRAPHS, 256, 0, stream>>>(ag, a_scopes, (float*)d_out);
}

// Round 6
// 4087.746 us; speedup vs baseline: 4.1681x; 4.1681x over previous
//
#include <hip/hip_runtime.h>

#define NATOMS 300000
#define NCOLS 8
#define VOCABSZ 4096
#define DCOL 32
#define HIDDIM 256
#define NBONDS 320000
#define NGRAPHS 6000
#define NSTEPS 3

constexpr int MP = 300032;             // atoms padded to multiple of 128
constexpr int GEMM_BLOCKS = MP / 128;  // 2344

// ---------------------------------------------------------------------------
// Global scratch pool, allocated ONCE at shared-library load time (dlopen),
// outside graph capture. Pre-faulted with hipMemset.
static void* g_pool = nullptr;
__attribute__((constructor)) static void alloc_pool() {
    void* p = nullptr;
    if (hipMalloc(&p, (size_t)960 * 1024 * 1024) == hipSuccess) {
        hipMemset(p, 0, (size_t)960 * 1024 * 1024);
        g_pool = p;
    }
}

// ---------------------------------------------------------------------------
__global__ void fill_kernel(float* out, float v, int n) {
    int i = blockIdx.x * blockDim.x + threadIdx.x;
    if (i < n) out[i] = v;
}

// ---------------------------------------------------------------------------
// Build per-dst linked lists of directed edges (src = concat(u,v), dst = concat(v,u))
__global__ void build_edges_kernel(const int* __restrict__ bf, int* __restrict__ esrc,
                                   int* __restrict__ nxt, int* head) {
    int e = blockIdx.x * blockDim.x + threadIdx.x;
    if (e >= 2 * NBONDS) return;
    int src, dst;
    if (e < NBONDS) { src = bf[e * 3 + 0]; dst = bf[e * 3 + 1]; }
    else { int i = e - NBONDS; src = bf[i * 3 + 1]; dst = bf[i * 3 + 0]; }
    esrc[e] = src;
    nxt[e] = atomicExch(&head[dst], e);
}

// ---------------------------------------------------------------------------
// Transpose W[rows][cols] -> Wt[cols][rows]
__global__ void transpose_kernel(const float* __restrict__ W, float* __restrict__ Wt,
                                 int rows, int cols) {
    int gid = blockIdx.x * blockDim.x + threadIdx.x;
    if (gid >= rows * cols) return;
    int n = gid / cols, k = gid % cols;
    Wt[k * rows + n] = W[gid];
}

__global__ void bsum_kernel(const float* __restrict__ a, const float* __restrict__ b,
                            float* __restrict__ o) {
    int i = threadIdx.x;
    o[i] = a[i] + b[i];
}

// ---------------------------------------------------------------------------
// Embedding: x[i][k] = sum_c emb[c][idx[i,c]][k]
__global__ void embed_kernel(const int* __restrict__ af, const float* __restrict__ emb,
                             float* __restrict__ x) {
    int gid = blockIdx.x * blockDim.x + threadIdx.x;
    int i = gid >> 5, k = gid & 31;
    if (i >= NATOMS) return;
    float s = 0.0f;
#pragma unroll
    for (int c = 0; c < NCOLS; c++) {
        int v = af[i * NCOLS + c];
        int idx = v & (VOCABSZ - 1);
        if (v >= 999999999) idx = 0;
        s += emb[((size_t)c * VOCABSZ + idx) * DCOL + k];
    }
    x[(size_t)i * DCOL + k] = s;
}

// ---------------------------------------------------------------------------
// Aggregation: agg[i][:] = sum over incoming edges of h[src][:]. One wave per atom.
__global__ void agg_kernel(const float* __restrict__ h, float* __restrict__ agg,
                           const int* __restrict__ head, const int* __restrict__ nxt,
                           const int* __restrict__ esrc) {
    int wid = (blockIdx.x * blockDim.x + threadIdx.x) >> 6;
    int lane = threadIdx.x & 63;
    if (wid >= NATOMS) return;
    float4 acc = make_float4(0.f, 0.f, 0.f, 0.f);
    int e = head[wid];
    while (e >= 0) {
        int src = esrc[e];
        float4 v = ((const float4*)(h + (size_t)src * HIDDIM))[lane];
        acc.x += v.x; acc.y += v.y; acc.z += v.z; acc.w += v.w;
        e = nxt[e];
    }
    ((float4*)(agg + (size_t)wid * HIDDIM))[lane] = acc;
}

// ---------------------------------------------------------------------------
// Fused GEMM v6 (r3 all-LDS structure, bigger tile):
//   C = act(A1 @ W1t + [A2 @ W2t] + bias)
// Tile: 128(M) x 256(N) per 256-thread block. Thread (tm=t>>5, tn=t&31)
// computes rows tm*16..+15 and cols {4tn..+3, 4tn+128..+131} (split columns
// keep W LDS reads lane-contiguous -> conflict-free; adjacent-8 would be
// 8-way conflicted). A staged k-major in LDS stride 132 (<=2-way on writes =
// free); A-frag reads are 32-lane broadcasts. Per kk per wave: 12 ds_read_b128
// for 256 FMAs (vs r3: 10 for 128) -> LDS-pipe time ~562us vs FMA floor 500us.
// NO global wave-uniform loads in the inner loop (r4/r5 failure: they
// scalarize to s_load chains, blow the SGPR file, and scalar-spill GBs).

#define FMA4(A, S, W)                       \
    A.x = fmaf((S), (W).x, A.x);            \
    A.y = fmaf((S), (W).y, A.y);            \
    A.z = fmaf((S), (W).z, A.z);            \
    A.w = fmaf((S), (W).w, A.w);

constexpr int ASTR = 132;  // LDS stride for A tiles (128 + 4)

template <bool HAS_A2, bool RELU, int K>
__global__ __launch_bounds__(256, 2) void gemm_kernel(
    const float* __restrict__ A1, const float* __restrict__ A2,
    const float* __restrict__ W1t, const float* __restrict__ W2t,
    const float* __restrict__ bias, float* __restrict__ C) {
    extern __shared__ float smem[];
    float* hs  = smem;                  // [16][ASTR] A1 tile, k-major
    float* w1s = smem + 16 * ASTR;      // [16][256]
    float* as2 = w1s + 16 * 256;        // [16][ASTR]  (HAS_A2 only)
    float* w2s = as2 + 16 * ASTR;       // [16][256]   (HAS_A2 only)

    const int t = threadIdx.x;
    const int tn = t & 31;   // col group: cols 4tn and 4tn+128
    const int tm = t >> 5;   // row group: rows tm*16..+15
    const int m0 = blockIdx.x * 128;
    const int ms = t >> 2;   // staging row 0..63 (phase 0), +64 (phase 1)
    const int js = t & 3;    // staging k-quad 0..3

    float4 acc0[16], acc1[16];
#pragma unroll
    for (int m = 0; m < 16; m++) {
        acc0[m] = make_float4(0.f, 0.f, 0.f, 0.f);
        acc1[m] = make_float4(0.f, 0.f, 0.f, 0.f);
    }

    for (int k0 = 0; k0 < K; k0 += 16) {
        __syncthreads();
#pragma unroll
        for (int p = 0; p < 2; p++) {
            const int row = ms + 64 * p;
            float4 v = *(const float4*)(A1 + (size_t)(m0 + row) * K + k0 + 4 * js);
            hs[(4 * js + 0) * ASTR + row] = v.x;
            hs[(4 * js + 1) * ASTR + row] = v.y;
            hs[(4 * js + 2) * ASTR + row] = v.z;
            hs[(4 * js + 3) * ASTR + row] = v.w;
        }
        if (HAS_A2) {
#pragma unroll
            for (int p = 0; p < 2; p++) {
                const int row = ms + 64 * p;
                float4 v = *(const float4*)(A2 + (size_t)(m0 + row) * K + k0 + 4 * js);
                as2[(4 * js + 0) * ASTR + row] = v.x;
                as2[(4 * js + 1) * ASTR + row] = v.y;
                as2[(4 * js + 2) * ASTR + row] = v.z;
                as2[(4 * js + 3) * ASTR + row] = v.w;
            }
        }
        {
            const float4* src = (const float4*)(W1t + (size_t)k0 * HIDDIM);
            float4* dst = (float4*)w1s;
#pragma unroll
            for (int i = 0; i < 4; i++) dst[t + 256 * i] = src[t + 256 * i];
        }
        if (HAS_A2) {
            const float4* src = (const float4*)(W2t + (size_t)k0 * HIDDIM);
            float4* dst = (float4*)w2s;
#pragma unroll
            for (int i = 0; i < 4; i++) dst[t + 256 * i] = src[t + 256 * i];
        }
        __syncthreads();

#pragma unroll
        for (int kk = 0; kk < 16; kk++) {
            {
                const float4 wa = *(const float4*)(w1s + kk * HIDDIM + 4 * tn);
                const float4 wb = *(const float4*)(w1s + kk * HIDDIM + 4 * tn + 128);
                const float4* ap = (const float4*)(hs + kk * ASTR + tm * 16);
#pragma unroll
                for (int q = 0; q < 4; q++) {
                    const float4 aq = ap[q];
                    FMA4(acc0[4 * q + 0], aq.x, wa); FMA4(acc1[4 * q + 0], aq.x, wb);
                    FMA4(acc0[4 * q + 1], aq.y, wa); FMA4(acc1[4 * q + 1], aq.y, wb);
                    FMA4(acc0[4 * q + 2], aq.z, wa); FMA4(acc1[4 * q + 2], aq.z, wb);
                    FMA4(acc0[4 * q + 3], aq.w, wa); FMA4(acc1[4 * q + 3], aq.w, wb);
                }
            }
            if (HAS_A2) {
                const float4 wa = *(const float4*)(w2s + kk * HIDDIM + 4 * tn);
                const float4 wb = *(const float4*)(w2s + kk * HIDDIM + 4 * tn + 128);
                const float4* gp = (const float4*)(as2 + kk * ASTR + tm * 16);
#pragma unroll
                for (int q = 0; q < 4; q++) {
                    const float4 gq = gp[q];
                    FMA4(acc0[4 * q + 0], gq.x, wa); FMA4(acc1[4 * q + 0], gq.x, wb);
                    FMA4(acc0[4 * q + 1], gq.y, wa); FMA4(acc1[4 * q + 1], gq.y, wb);
                    FMA4(acc0[4 * q + 2], gq.z, wa); FMA4(acc1[4 * q + 2], gq.z, wb);
                    FMA4(acc0[4 * q + 3], gq.w, wa); FMA4(acc1[4 * q + 3], gq.w, wb);
                }
            }
        }
    }

    const float4 b4a = *(const float4*)(bias + 4 * tn);
    const float4 b4b = *(const float4*)(bias + 4 * tn + 128);
#pragma unroll
    for (int m = 0; m < 16; m++) {
        float4 oa, ob;
        oa.x = acc0[m].x + b4a.x; oa.y = acc0[m].y + b4a.y;
        oa.z = acc0[m].z + b4a.z; oa.w = acc0[m].w + b4a.w;
        ob.x = acc1[m].x + b4b.x; ob.y = acc1[m].y + b4b.y;
        ob.z = acc1[m].z + b4b.z; ob.w = acc1[m].w + b4b.w;
        if (RELU) {
            oa.x = fmaxf(oa.x, 0.f); oa.y = fmaxf(oa.y, 0.f);
            oa.z = fmaxf(oa.z, 0.f); oa.w = fmaxf(oa.w, 0.f);
            ob.x = fmaxf(ob.x, 0.f); ob.y = fmaxf(ob.y, 0.f);
            ob.z = fmaxf(ob.z, 0.f); ob.w = fmaxf(ob.w, 0.f);
        }
        float* crow = C + (size_t)(m0 + tm * 16 + m) * HIDDIM;
        *(float4*)(crow + 4 * tn) = oa;
        *(float4*)(crow + 4 * tn + 128) = ob;
    }
}

// ---------------------------------------------------------------------------
// Readout: out[g][n] = mean over atoms in graph g
__global__ void readout_kernel(const float* __restrict__ h, const int* __restrict__ scopes,
                               float* __restrict__ out) {
    int g = blockIdx.x;
    int n = threadIdx.x;
    int start = scopes[g * 2 + 0];
    int len = scopes[g * 2 + 1];
    float s = 0.f;
    for (int j = 0; j < len; j++) s += h[(size_t)(start + j) * HIDDIM + n];
    int d = len > 1 ? len : 1;
    out[(size_t)g * HIDDIM + n] = s / (float)d;
}

// ---------------------------------------------------------------------------
extern "C" void kernel_launch(void* const* d_in, const int* in_sizes, int n_in,
                              void* d_out, int out_size, void* d_ws, size_t ws_size,
                              hipStream_t stream) {
    const int* a_features = (const int*)d_in[0];
    const int* b_features = (const int*)d_in[1];
    const int* a_scopes   = (const int*)d_in[2];
    const float* emb      = (const float*)d_in[3];
    const float* W_in     = (const float*)d_in[4];
    const float* b_in     = (const float*)d_in[5];
    const float* W_self   = (const float*)d_in[6];
    const float* b_self   = (const float*)d_in[7];
    const float* W_neigh  = (const float*)d_in[8];
    const float* b_neigh  = (const float*)d_in[9];
    const float* W_out    = (const float*)d_in[10];
    const float* b_out    = (const float*)d_in[11];

    if (g_pool == nullptr) {
        fill_kernel<<<(out_size + 255) / 256, 256, 0, stream>>>(
            (float*)d_out, 77777.0f, out_size);
        return;
    }

    float* ws = (float*)g_pool;
    const size_t HBUF = (size_t)MP * HIDDIM;   // 76,808,192 floats
    float* bufA = ws;
    float* bufB = ws + HBUF;
    float* bufC = ws + 2 * HBUF;
    float* Wit  = ws + 3 * HBUF;               // [32][256]
    float* Wst  = Wit + (size_t)DCOL * HIDDIM; // [256][256]
    float* Wnt  = Wst + (size_t)HIDDIM * HIDDIM;
    float* Wot  = Wnt + (size_t)HIDDIM * HIDDIM;
    float* bsum = Wot + (size_t)HIDDIM * HIDDIM;
    int* esrc = (int*)(bsum + HIDDIM);
    int* nxt  = esrc + 2 * NBONDS;
    int* head = nxt + 2 * NBONDS;

    constexpr int SMEM_SMALL = (16 * ASTR + 16 * HIDDIM) * 4;  // 24832 B
    constexpr int SMEM_BIG   = 2 * SMEM_SMALL;                 // 49664 B
    constexpr int NPAD = MP - NATOMS;                          // 32 pad rows

    // --- setup (identical every launch) ---
    hipMemsetAsync(head, 0xFF, (size_t)MP * sizeof(int), stream);
    build_edges_kernel<<<(2 * NBONDS + 255) / 256, 256, 0, stream>>>(b_features, esrc, nxt, head);
    transpose_kernel<<<(HIDDIM * DCOL + 255) / 256, 256, 0, stream>>>(W_in, Wit, HIDDIM, DCOL);
    transpose_kernel<<<(HIDDIM * HIDDIM + 255) / 256, 256, 0, stream>>>(W_self, Wst, HIDDIM, HIDDIM);
    transpose_kernel<<<(HIDDIM * HIDDIM + 255) / 256, 256, 0, stream>>>(W_neigh, Wnt, HIDDIM, HIDDIM);
    transpose_kernel<<<(HIDDIM * HIDDIM + 255) / 256, 256, 0, stream>>>(W_out, Wot, HIDDIM, HIDDIM);
    bsum_kernel<<<1, HIDDIM, 0, stream>>>(b_self, b_neigh, bsum);

    // Zero the padding rows (pool is persistent, never harness-poisoned).
    fill_kernel<<<(NPAD * HIDDIM + 255) / 256, 256, 0, stream>>>(bufA + (size_t)NATOMS * HIDDIM, 0.f, NPAD * HIDDIM);
    fill_kernel<<<(NPAD * HIDDIM + 255) / 256, 256, 0, stream>>>(bufB + (size_t)NATOMS * HIDDIM, 0.f, NPAD * HIDDIM);
    fill_kernel<<<(NPAD * HIDDIM + 255) / 256, 256, 0, stream>>>(bufC + (size_t)NATOMS * HIDDIM, 0.f, NPAD * HIDDIM);
    fill_kernel<<<(NPAD * DCOL + 255) / 256, 256, 0, stream>>>(bufB + (size_t)NATOMS * DCOL, 0.f, NPAD * DCOL);

    // --- embedding + input linear (x aliased into bufB, row stride DCOL) ---
    embed_kernel<<<(NATOMS * DCOL + 255) / 256, 256, 0, stream>>>(a_features, emb, bufB);
    gemm_kernel<false, false, DCOL><<<GEMM_BLOCKS, 256, SMEM_SMALL, stream>>>(
        bufB, nullptr, Wit, nullptr, b_in, bufA);

    // --- 3 message-passing steps with rotating buffers ---
    float* h  = bufA;
    float* ag = bufB;
    float* hn = bufC;
    for (int s = 0; s < NSTEPS; s++) {
        agg_kernel<<<NATOMS / 4, 256, 0, stream>>>(h, ag, head, nxt, esrc);
        gemm_kernel<true, true, HIDDIM><<<GEMM_BLOCKS, 256, SMEM_BIG, stream>>>(
            h, ag, Wst, Wnt, bsum, hn);
        float* oldh = h;
        h = hn; hn = ag; ag = oldh;
    }

    // --- output linear + readout ---
    gemm_kernel<false, false, HIDDIM><<<GEMM_BLOCKS, 256, SMEM_SMALL, stream>>>(
        h, nullptr, Wot, nullptr, b_out, ag);
    readout_kernel<<<NGRAPHS, 256, 0, stream>>>(ag, a_scopes, (float*)d_out);
}

// Round 8
// 2289.832 us; speedup vs baseline: 7.4407x; 1.7852x over previous
//
#include <hip/hip_runtime.h>

#define NATOMS 300000
#define NCOLS 8
#define VOCABSZ 4096
#define DCOL 32
#define HIDDIM 256
#define NBONDS 320000
#define NGRAPHS 6000
#define NSTEPS 3

constexpr int MP = 300032;             // atoms padded to multiple of 128
constexpr int MTILES = MP / 128;       // 2344

typedef _Float16 f16;
typedef _Float16 f16x4 __attribute__((ext_vector_type(4)));
typedef _Float16 f16x8 __attribute__((ext_vector_type(8)));
typedef float f32x4 __attribute__((ext_vector_type(4)));

constexpr float LO_SCALE = 2048.0f;      // 2^11: keeps lo parts in fp16 NORMAL range
constexpr float INV_LO   = 1.0f / 2048.0f;

__device__ __forceinline__ void split2(float x, f16& h, f16& l) {
    h = (f16)x;
    l = (f16)((x - (float)h) * LO_SCALE);
}

// ---------------------------------------------------------------------------
// Global scratch pool, allocated ONCE at shared-library load (outside capture).
static void* g_pool = nullptr;
__attribute__((constructor)) static void alloc_pool() {
    void* p = nullptr;
    if (hipMalloc(&p, (size_t)1024 * 1024 * 1024) == hipSuccess) {
        hipMemset(p, 0, (size_t)1024 * 1024 * 1024);
        g_pool = p;
    }
}

// ---------------------------------------------------------------------------
__global__ void fill_kernel(float* out, float v, int n) {
    int i = blockIdx.x * blockDim.x + threadIdx.x;
    if (i < n) out[i] = v;
}

// ---------------------------------------------------------------------------
__global__ void build_edges_kernel(const int* __restrict__ bf, int* __restrict__ esrc,
                                   int* __restrict__ nxt, int* head) {
    int e = blockIdx.x * blockDim.x + threadIdx.x;
    if (e >= 2 * NBONDS) return;
    int src, dst;
    if (e < NBONDS) { src = bf[e * 3 + 0]; dst = bf[e * 3 + 1]; }
    else { int i = e - NBONDS; src = bf[i * 3 + 1]; dst = bf[i * 3 + 0]; }
    esrc[e] = src;
    nxt[e] = atomicExch(&head[dst], e);
}

// ---------------------------------------------------------------------------
// Split fp32 W[n][k] row-major into fp16 hi + scaled-lo (same layout; this IS
// the MFMA B-operand layout Bt[n][k], no transpose needed).
__global__ void wsplit_kernel(const float* __restrict__ W, f16* __restrict__ Wh,
                              f16* __restrict__ Wl, int n) {
    int i = blockIdx.x * blockDim.x + threadIdx.x;
    if (i >= n) return;
    split2(W[i], Wh[i], Wl[i]);
}

__global__ void bsum_kernel(const float* __restrict__ a, const float* __restrict__ b,
                            float* __restrict__ o) {
    int i = threadIdx.x;
    o[i] = a[i] + b[i];
}

// ---------------------------------------------------------------------------
// Embedding: x[i][k] = sum_c emb[c][idx[i,c]][k], written as fp16 pair.
__global__ void embed_kernel(const int* __restrict__ af, const float* __restrict__ emb,
                             f16* __restrict__ xh, f16* __restrict__ xl) {
    int gid = blockIdx.x * blockDim.x + threadIdx.x;
    int i = gid >> 5, k = gid & 31;
    if (i >= NATOMS) return;
    float s = 0.0f;
#pragma unroll
    for (int c = 0; c < NCOLS; c++) {
        int v = af[i * NCOLS + c];
        int idx = v & (VOCABSZ - 1);
        if (v >= 999999999) idx = 0;
        s += emb[((size_t)c * VOCABSZ + idx) * DCOL + k];
    }
    split2(s, xh[(size_t)i * DCOL + k], xl[(size_t)i * DCOL + k]);
}

// ---------------------------------------------------------------------------
// Aggregation over fp16-pair state. One wave per atom; lane owns 4 columns.
__global__ void agg_kernel(const f16* __restrict__ Ahi, const f16* __restrict__ Alo,
                           f16* __restrict__ Ghi, f16* __restrict__ Glo,
                           const int* __restrict__ head, const int* __restrict__ nxt,
                           const int* __restrict__ esrc) {
    int wid = (blockIdx.x * blockDim.x + threadIdx.x) >> 6;
    int lane = threadIdx.x & 63;
    if (wid >= NATOMS) return;
    float4 sh = make_float4(0.f, 0.f, 0.f, 0.f);
    float4 sl = make_float4(0.f, 0.f, 0.f, 0.f);
    int e = head[wid];
    while (e >= 0) {
        int src = esrc[e];
        const f16x4 vh = *(const f16x4*)(Ahi + (size_t)src * HIDDIM + lane * 4);
        const f16x4 vl = *(const f16x4*)(Alo + (size_t)src * HIDDIM + lane * 4);
        sh.x += (float)vh.x; sh.y += (float)vh.y; sh.z += (float)vh.z; sh.w += (float)vh.w;
        sl.x += (float)vl.x; sl.y += (float)vl.y; sl.z += (float)vl.z; sl.w += (float)vl.w;
        e = nxt[e];
    }
    float4 s;
    s.x = sh.x + sl.x * INV_LO; s.y = sh.y + sl.y * INV_LO;
    s.z = sh.z + sl.z * INV_LO; s.w = sh.w + sl.w * INV_LO;
    // split via scalar temporaries (can't bind refs to vector elements)
    f16 h0, l0, h1, l1, h2, l2, h3, l3;
    split2(s.x, h0, l0); split2(s.y, h1, l1);
    split2(s.z, h2, l2); split2(s.w, h3, l3);
    f16x4 oh, ol;
    oh.x = h0; oh.y = h1; oh.z = h2; oh.w = h3;
    ol.x = l0; ol.y = l1; ol.z = l2; ol.w = l3;
    *(f16x4*)(Ghi + (size_t)wid * HIDDIM + lane * 4) = oh;
    *(f16x4*)(Glo + (size_t)wid * HIDDIM + lane * 4) = ol;
}

// ---------------------------------------------------------------------------
// MFMA GEMM with fp16 hi/lo split:
//   C = act( A1@B1^T + [A2@B2^T] + bias ),  A [MP][K] fp32-as-pairs,
//   B given as W[n][k] fp16 pairs (lo pre-scaled by 2048).
// Terms per matrix: Ah*Bh -> acc_hi;  Ah*Bl' + Al'*Bh -> acc_lo;
// epilogue: v = acc_hi + acc_lo/2048 + bias.
// Block: 256 thr = 4 waves (2x2), block tile 128(M) x 128(N), grid (2, MTILES).
// Wave tile 64x64 = 4x4 subtiles of 16x16, mfma_f32_16x16x32_f16, K-chunk 32.
// LDS: 4 tiles [128][40] halves (pad 40 -> 2-way conflicts only = free).
// Fragment layouts (HW-verified per learn_hip m89/m91 notes):
//   A[m=lane&15][k=quad*8+j], B[k=quad*8+j][n=lane&15] (from Bt[n][k] rows),
//   C/D: col=lane&15, row=quad*4+reg.
template <bool HAS_A2, bool RELU, int K>
__global__ __launch_bounds__(256, 2) void mfma_gemm(
    const f16* __restrict__ A1h, const f16* __restrict__ A1l,
    const f16* __restrict__ A2h, const f16* __restrict__ A2l,
    const f16* __restrict__ B1h, const f16* __restrict__ B1l,
    const f16* __restrict__ B2h, const f16* __restrict__ B2l,
    const float* __restrict__ bias,
    f16* __restrict__ Chi, f16* __restrict__ Clo) {
    __shared__ __align__(16) f16 sAh[128 * 40];
    __shared__ __align__(16) f16 sAl[128 * 40];
    __shared__ __align__(16) f16 sBh[128 * 40];
    __shared__ __align__(16) f16 sBl[128 * 40];

    const int t = threadIdx.x;
    const int n0 = blockIdx.x * 128;
    const int m0 = blockIdx.y * 128;
    const int lane = t & 63;
    const int wid = t >> 6;
    const int wm = (wid >> 1) * 64;
    const int wn = (wid & 1) * 64;
    const int quad = lane >> 4;
    const int l16 = lane & 15;

    f32x4 acch[4][4], accl[4][4];
#pragma unroll
    for (int a = 0; a < 4; a++)
#pragma unroll
        for (int b = 0; b < 4; b++) {
            acch[a][b] = (f32x4){0.f, 0.f, 0.f, 0.f};
            accl[a][b] = (f32x4){0.f, 0.f, 0.f, 0.f};
        }

    const int NMAT = HAS_A2 ? 2 : 1;
    for (int kb = 0; kb < K; kb += 32) {
        for (int mat = 0; mat < NMAT; mat++) {
            const f16* Ah = (mat == 0) ? A1h : A2h;
            const f16* Al = (mat == 0) ? A1l : A2l;
            const f16* Bh = (mat == 0) ? B1h : B2h;
            const f16* Bl = (mat == 0) ? B1l : B2l;
            __syncthreads();
#pragma unroll
            for (int i = 0; i < 2; i++) {
                const int c = t + 256 * i;     // 0..511
                const int r = c >> 2, q = c & 3;
                *(int4*)(sAh + r * 40 + q * 8) = *(const int4*)(Ah + (size_t)(m0 + r) * K + kb + q * 8);
                *(int4*)(sAl + r * 40 + q * 8) = *(const int4*)(Al + (size_t)(m0 + r) * K + kb + q * 8);
                *(int4*)(sBh + r * 40 + q * 8) = *(const int4*)(Bh + (size_t)(n0 + r) * K + kb + q * 8);
                *(int4*)(sBl + r * 40 + q * 8) = *(const int4*)(Bl + (size_t)(n0 + r) * K + kb + q * 8);
            }
            __syncthreads();

            f16x8 fah[4], fal[4];
#pragma unroll
            for (int mt = 0; mt < 4; mt++) {
                fah[mt] = *(const f16x8*)(sAh + (wm + mt * 16 + l16) * 40 + quad * 8);
                fal[mt] = *(const f16x8*)(sAl + (wm + mt * 16 + l16) * 40 + quad * 8);
            }
#pragma unroll
            for (int nt = 0; nt < 4; nt++) {
                const f16x8 bh = *(const f16x8*)(sBh + (wn + nt * 16 + l16) * 40 + quad * 8);
                const f16x8 bl = *(const f16x8*)(sBl + (wn + nt * 16 + l16) * 40 + quad * 8);
#pragma unroll
                for (int mt = 0; mt < 4; mt++) {
                    acch[mt][nt] = __builtin_amdgcn_mfma_f32_16x16x32_f16(fah[mt], bh, acch[mt][nt], 0, 0, 0);
                    accl[mt][nt] = __builtin_amdgcn_mfma_f32_16x16x32_f16(fah[mt], bl, accl[mt][nt], 0, 0, 0);
                    accl[mt][nt] = __builtin_amdgcn_mfma_f32_16x16x32_f16(fal[mt], bh, accl[mt][nt], 0, 0, 0);
                }
            }
        }
    }

#pragma unroll
    for (int mt = 0; mt < 4; mt++) {
#pragma unroll
        for (int nt = 0; nt < 4; nt++) {
            const int col = n0 + wn + nt * 16 + l16;
            const float bv = bias[col];
#pragma unroll
            for (int r = 0; r < 4; r++) {
                const int row = m0 + wm + mt * 16 + quad * 4 + r;
                float v = acch[mt][nt][r] + accl[mt][nt][r] * INV_LO + bv;
                if (RELU) v = fmaxf(v, 0.f);
                f16 hi, lo;
                split2(v, hi, lo);
                Chi[(size_t)row * HIDDIM + col] = hi;
                Clo[(size_t)row * HIDDIM + col] = lo;
            }
        }
    }
}

// ---------------------------------------------------------------------------
// Readout from fp16-pair state: out[g][n] = mean over atoms in graph g (fp32).
__global__ void readout_kernel(const f16* __restrict__ Hhi, const f16* __restrict__ Hlo,
                               const int* __restrict__ scopes, float* __restrict__ out) {
    int g = blockIdx.x;
    int n = threadIdx.x;
    int start = scopes[g * 2 + 0];
    int len = scopes[g * 2 + 1];
    float s = 0.f;
    for (int j = 0; j < len; j++) {
        size_t o = (size_t)(start + j) * HIDDIM + n;
        s += (float)Hhi[o] + (float)Hlo[o] * INV_LO;
    }
    int d = len > 1 ? len : 1;
    out[(size_t)g * HIDDIM + n] = s / (float)d;
}

// ---------------------------------------------------------------------------
extern "C" void kernel_launch(void* const* d_in, const int* in_sizes, int n_in,
                              void* d_out, int out_size, void* d_ws, size_t ws_size,
                              hipStream_t stream) {
    const int* a_features = (const int*)d_in[0];
    const int* b_features = (const int*)d_in[1];
    const int* a_scopes   = (const int*)d_in[2];
    const float* emb      = (const float*)d_in[3];
    const float* W_in     = (const float*)d_in[4];
    const float* b_in     = (const float*)d_in[5];
    const float* W_self   = (const float*)d_in[6];
    const float* b_self   = (const float*)d_in[7];
    const float* W_neigh  = (const float*)d_in[8];
    const float* b_neigh  = (const float*)d_in[9];
    const float* W_out    = (const float*)d_in[10];
    const float* b_out    = (const float*)d_in[11];

    if (g_pool == nullptr) {
        fill_kernel<<<(out_size + 255) / 256, 256, 0, stream>>>(
            (float*)d_out, 77777.0f, out_size);
        return;
    }

    // ---- pool layout (halves) ----
    f16* p = (f16*)g_pool;
    const size_t HB = (size_t)MP * HIDDIM;       // 76,808,192 halves
    f16* hAhi = p;            f16* hAlo = p + HB;
    f16* hBhi = p + 2 * HB;   f16* hBlo = p + 3 * HB;
    f16* hChi = p + 4 * HB;   f16* hClo = p + 5 * HB;
    f16* xhi  = p + 6 * HB;
    f16* xlo  = xhi + (size_t)MP * DCOL;
    f16* Winh = xlo + (size_t)MP * DCOL;
    f16* Winl = Winh + HIDDIM * DCOL;
    f16* Wsh  = Winl + HIDDIM * DCOL;
    f16* Wsl  = Wsh + HIDDIM * HIDDIM;
    f16* Wnh  = Wsl + HIDDIM * HIDDIM;
    f16* Wnl  = Wnh + HIDDIM * HIDDIM;
    f16* Woh  = Wnl + HIDDIM * HIDDIM;
    f16* Wol  = Woh + HIDDIM * HIDDIM;
    float* bsum = (float*)(Wol + HIDDIM * HIDDIM);
    int* esrc = (int*)(bsum + HIDDIM);
    int* nxt  = esrc + 2 * NBONDS;
    int* head = nxt + 2 * NBONDS;

    constexpr int NPAD = MP - NATOMS;            // 32 pad rows

    // ---- setup (identical every launch) ----
    hipMemsetAsync(head, 0xFF, (size_t)MP * sizeof(int), stream);
    build_edges_kernel<<<(2 * NBONDS + 255) / 256, 256, 0, stream>>>(b_features, esrc, nxt, head);
    wsplit_kernel<<<(HIDDIM * DCOL + 255) / 256, 256, 0, stream>>>(W_in, Winh, Winl, HIDDIM * DCOL);
    wsplit_kernel<<<(HIDDIM * HIDDIM + 255) / 256, 256, 0, stream>>>(W_self, Wsh, Wsl, HIDDIM * HIDDIM);
    wsplit_kernel<<<(HIDDIM * HIDDIM + 255) / 256, 256, 0, stream>>>(W_neigh, Wnh, Wnl, HIDDIM * HIDDIM);
    wsplit_kernel<<<(HIDDIM * HIDDIM + 255) / 256, 256, 0, stream>>>(W_out, Woh, Wol, HIDDIM * HIDDIM);
    bsum_kernel<<<1, HIDDIM, 0, stream>>>(b_self, b_neigh, bsum);

    // Zero padding rows of every pair buffer (pool is persistent).
    constexpr int PADF = NPAD * HIDDIM / 2;      // halves -> floats
    fill_kernel<<<(PADF + 255) / 256, 256, 0, stream>>>((float*)(hAhi + (size_t)NATOMS * HIDDIM), 0.f, PADF);
    fill_kernel<<<(PADF + 255) / 256, 256, 0, stream>>>((float*)(hAlo + (size_t)NATOMS * HIDDIM), 0.f, PADF);
    fill_kernel<<<(PADF + 255) / 256, 256, 0, stream>>>((float*)(hBhi + (size_t)NATOMS * HIDDIM), 0.f, PADF);
    fill_kernel<<<(PADF + 255) / 256, 256, 0, stream>>>((float*)(hBlo + (size_t)NATOMS * HIDDIM), 0.f, PADF);
    fill_kernel<<<(PADF + 255) / 256, 256, 0, stream>>>((float*)(hChi + (size_t)NATOMS * HIDDIM), 0.f, PADF);
    fill_kernel<<<(PADF + 255) / 256, 256, 0, stream>>>((float*)(hClo + (size_t)NATOMS * HIDDIM), 0.f, PADF);
    constexpr int PADX = NPAD * DCOL / 2;
    fill_kernel<<<(PADX + 255) / 256, 256, 0, stream>>>((float*)(xhi + (size_t)NATOMS * DCOL), 0.f, PADX);
    fill_kernel<<<(PADX + 255) / 256, 256, 0, stream>>>((float*)(xlo + (size_t)NATOMS * DCOL), 0.f, PADX);

    const dim3 ggrid(2, MTILES);

    // ---- embedding + input linear -> h (pair bufA) ----
    embed_kernel<<<(NATOMS * DCOL + 255) / 256, 256, 0, stream>>>(a_features, emb, xhi, xlo);
    mfma_gemm<false, false, DCOL><<<ggrid, 256, 0, stream>>>(
        xhi, xlo, nullptr, nullptr, Winh, Winl, nullptr, nullptr, b_in, hAhi, hAlo);

    // ---- 3 message-passing steps with rotating pair buffers ----
    f16 *h_hi = hAhi, *h_lo = hAlo;
    f16 *g_hi = hBhi, *g_lo = hBlo;
    f16 *n_hi = hChi, *n_lo = hClo;
    for (int s = 0; s < NSTEPS; s++) {
        agg_kernel<<<NATOMS / 4, 256, 0, stream>>>(h_hi, h_lo, g_hi, g_lo, head, nxt, esrc);
        mfma_gemm<true, true, HIDDIM><<<ggrid, 256, 0, stream>>>(
            h_hi, h_lo, g_hi, g_lo, Wsh, Wsl, Wnh, Wnl, bsum, n_hi, n_lo);
        f16* t1 = h_hi; f16* t2 = h_lo;
        h_hi = n_hi; h_lo = n_lo;
        n_hi = g_hi; n_lo = g_lo;
        g_hi = t1;   g_lo = t2;
    }

    // ---- output linear (into free pair buffer) + readout ----
    mfma_gemm<false, false, HIDDIM><<<ggrid, 256, 0, stream>>>(
        h_hi, h_lo, nullptr, nullptr, Woh, Wol, nullptr, nullptr, b_out, g_hi, g_lo);
    readout_kernel<<<NGRAPHS, 256, 0, stream>>>(g_hi, g_lo, a_scopes, (float*)d_out);
}